// Round 9
// baseline (1078.235 us; speedup 1.0000x reference)
//
#include <hip/hip_runtime.h>
#include <hip/hip_fp16.h>

#define NN 100000
#define EE 1600000
#define GG 512
#define NB ((NN + 255) / 256)   // 391 blocks for node-sized scans

// ---- in-degree histogram (int) ----
__global__ void deg_kernel(const int* __restrict__ ei, int* __restrict__ cnt, int E_) {
    int e = blockIdx.x * 256 + threadIdx.x;
    if (e < E_) atomicAdd(&cnt[ei[E_ + e]], 1);
}

// ---- dinv = 1/sqrt(cnt + 1 self-loop) ----
__global__ void dinv_kernel(const int* __restrict__ cnt, float* __restrict__ dinv, int n) {
    int i = blockIdx.x * 256 + threadIdx.x;
    if (i < n) dinv[i] = rsqrtf((float)cnt[i] + 1.0f);
}

// ---- block sums for scan ----
__global__ void blocksum(const int* __restrict__ cnt, int* __restrict__ bsum) {
    __shared__ int sh[256];
    int i = blockIdx.x * 256 + threadIdx.x;
    sh[threadIdx.x] = (i < NN) ? cnt[i] : 0;
    __syncthreads();
    for (int o = 128; o > 0; o >>= 1) {
        if (threadIdx.x < o) sh[threadIdx.x] += sh[threadIdx.x + o];
        __syncthreads();
    }
    if (threadIdx.x == 0) bsum[blockIdx.x] = sh[0];
}

// ---- exclusive scan of block sums (1 block, 512 threads, nb<=512) ----
__global__ void scan_bsum(int* __restrict__ bsum, int nb) {
    __shared__ int sh[512];
    int t = threadIdx.x;
    int v = (t < nb) ? bsum[t] : 0;
    int orig = v;
    sh[t] = v;
    __syncthreads();
    for (int o = 1; o < 512; o <<= 1) {
        int add = (t >= o) ? sh[t - o] : 0;
        __syncthreads();
        sh[t] += add;
        __syncthreads();
    }
    if (t < nb) bsum[t] = sh[t] - orig;   // exclusive
}

// ---- final scan: row_ptr + cursor ----
__global__ void scan_final(const int* __restrict__ cnt, const int* __restrict__ boff,
                           int* __restrict__ row_ptr, int* __restrict__ cursor) {
    __shared__ int sh[256];
    int i = blockIdx.x * 256 + threadIdx.x;
    int v = (i < NN) ? cnt[i] : 0;
    int orig = v;
    sh[threadIdx.x] = v;
    __syncthreads();
    for (int o = 1; o < 256; o <<= 1) {
        int add = (threadIdx.x >= o) ? sh[threadIdx.x - o] : 0;
        __syncthreads();
        sh[threadIdx.x] += add;
        __syncthreads();
    }
    if (i < NN) {
        int ex = boff[blockIdx.x] + sh[threadIdx.x] - orig;
        row_ptr[i] = ex;
        cursor[i] = ex;
    }
    if (i == 0) row_ptr[NN] = EE;
}

// ---- fill CSR: one packed 8B record per edge {src, norm=dinv[s]*dinv[d]} ----
__global__ void fill_csr(const int* __restrict__ ei, const float* __restrict__ dinv,
                         int* __restrict__ cursor, uint2* __restrict__ csr, int E_) {
    int e = blockIdx.x * 256 + threadIdx.x;
    if (e < E_) {
        int s = ei[e], d = ei[E_ + e];
        int pos = atomicAdd(&cursor[d], 1);
        uint2 rec;
        rec.x = (unsigned)s;
        rec.y = __float_as_uint(dinv[s] * dinv[d]);
        csr[pos] = rec;
    }
}

// ---- column stats: stats[0:64]=sum, stats[64:128]=sumsq (fp32 input) ----
__global__ void colstats(const float* __restrict__ A, int nrows, float* __restrict__ stats) {
    __shared__ float ssum[4][64];
    __shared__ float ssq[4][64];
    int tid = threadIdx.x;
    int col = tid & 63, rg = tid >> 6;
    float s = 0.f, q = 0.f;
    for (int r = blockIdx.x * 4 + rg; r < nrows; r += gridDim.x * 4) {
        float v = A[r * 64 + col];
        s += v;
        q = fmaf(v, v, q);
    }
    ssum[rg][col] = s; ssq[rg][col] = q;
    __syncthreads();
    if (tid < 64) {
        float ts = ssum[0][tid] + ssum[1][tid] + ssum[2][tid] + ssum[3][tid];
        float tq = ssq[0][tid] + ssq[1][tid] + ssq[2][tid] + ssq[3][tid];
        atomicAdd(&stats[tid], ts);
        atomicAdd(&stats[64 + tid], tq);
    }
}

// ---- fused BN-fold + C = (relu?)(BN(A)@W + basebias); A fp32;
//      C fp32 and/or fp16; optional fused column stats of C ----
__global__ __launch_bounds__(256) void gemm64f(const float* __restrict__ A32,
                                               const float* __restrict__ W,
                                               const float* __restrict__ g,
                                               const float* __restrict__ b,
                                               const float* __restrict__ basebias,
                                               const float* __restrict__ statsIn, float count,
                                               float* __restrict__ C32,
                                               __half* __restrict__ C16,
                                               int nrows, int dorelu,
                                               float* __restrict__ statsOut) {
    __shared__ float Ws[64 * 64];
    __shared__ float As[64 * 64];
    __shared__ float afold[64];
    __shared__ float cfold[64];
    __shared__ float ssh[256];
    __shared__ float qsh[256];
    int tid = threadIdx.x;
    if (tid < 64) {
        float mu  = statsIn[tid] / count;
        float var = fmaxf(statsIn[64 + tid] / count - mu * mu, 0.f);
        float rstd = rsqrtf(var + 1e-5f);
        float a = rstd * g[tid];
        afold[tid] = a;
        cfold[tid] = b[tid] - mu * a;
    }
    __syncthreads();
    int row0 = blockIdx.x * 64;
    for (int i = tid; i < 4096; i += 256) {
        Ws[i] = afold[i >> 6] * W[i];
        int r = row0 + (i >> 6);
        As[i] = (r < nrows) ? A32[row0 * 64 + i] : 0.f;
    }
    __syncthreads();
    int col = tid & 63;
    int rg = tid >> 6;  // 0..3
    // folded bias for this column
    float bcol = basebias ? basebias[col] : 0.f;
    for (int k = 0; k < 64; k++) bcol = fmaf(cfold[k], W[k * 64 + col], bcol);
    float s = 0.f, q = 0.f;
    for (int rr = rg; rr < 64; rr += 4) {
        int r = row0 + rr;
        if (r >= nrows) break;
        float acc = bcol;
#pragma unroll
        for (int k = 0; k < 64; k++) acc = fmaf(As[rr * 64 + k], Ws[k * 64 + col], acc);
        float v = dorelu ? fmaxf(acc, 0.f) : acc;
        if (C32) C32[r * 64 + col] = v;
        if (C16) C16[r * 64 + col] = __float2half(v);
        s += v;
        q = fmaf(v, v, q);
    }
    if (statsOut) {
        ssh[tid] = s; qsh[tid] = q;
        __syncthreads();
        if (tid < 64) {
            float ts = ssh[tid] + ssh[64 + tid] + ssh[128 + tid] + ssh[192 + tid];
            float tq = qsh[tid] + qsh[64 + tid] + qsh[128 + tid] + qsh[192 + tid];
            atomicAdd(&statsOut[tid], ts);
            atomicAdd(&statsOut[64 + tid], tq);
        }
    }
}

// ---- unpack 4 consecutive fp16 feats (8B) from a row ----
__device__ __forceinline__ void row4(const __half* __restrict__ base, int cl,
                                     float& x, float& y, float& z, float& w) {
    uint2 raw = ((const uint2*)base)[cl];
    __half2 h01 = *reinterpret_cast<const __half2*>(&raw.x);
    __half2 h23 = *reinterpret_cast<const __half2*>(&raw.y);
    float2 f01 = __half22float2(h01);
    float2 f23 = __half22float2(h23);
    x = f01.x; y = f01.y; z = f23.x; w = f23.y;
}

// ---- fused CSR gather (m fp16, h fp32; packed 8B edge records):
//      hn = h + relu(dinv^2*m[i] + sum_e norm*m[src] + cb)
//      h kept fp32 on this path (h16 measured +19us/dispatch, R7/R8 vs R2/R5).
//      optional: write h, next-layer BN stats, atomic pool ----
__global__ __launch_bounds__(256) void gather(const int* __restrict__ row_ptr,
                                              const uint2* __restrict__ csr,
                                              const float* __restrict__ dinv,
                                              const __half* __restrict__ m,
                                              float* __restrict__ h,
                                              const float* __restrict__ cb,
                                              float* __restrict__ stats,
                                              float* __restrict__ pooled,
                                              const int* __restrict__ batch,
                                              int writeH) {
    int tid = threadIdx.x;
    int ng = tid >> 4;        // 16 nodes per block
    int cl = tid & 15;        // 16 col-groups of 4
    const float4* cb4 = (const float4*)cb;
    float4 cbv = cb4[cl];
    float sx = 0.f, sy = 0.f, sz = 0.f, sw = 0.f;
    float qx = 0.f, qy = 0.f, qz = 0.f, qw = 0.f;
    for (int i = blockIdx.x * 16 + ng; i < NN; i += gridDim.x * 16) {
        float di = dinv[i];
        float mx, my, mz, mw;
        row4(m + (size_t)i * 64, cl, mx, my, mz, mw);
        float d2 = di * di;
        float ax = d2 * mx, ay = d2 * my, az = d2 * mz, aw = d2 * mw;
        int e0 = row_ptr[i], e1 = row_ptr[i + 1];
        int e = e0;
        // 4-wide unroll: 4 independent row loads in flight per node-group
        for (; e + 3 < e1; e += 4) {
            uint2 r0 = csr[e + 0];
            uint2 r1 = csr[e + 1];
            uint2 r2 = csr[e + 2];
            uint2 r3 = csr[e + 3];
            int s0 = (int)r0.x, s1 = (int)r1.x, s2 = (int)r2.x, s3 = (int)r3.x;
            float w0 = __uint_as_float(r0.y);
            float w1 = __uint_as_float(r1.y);
            float w2 = __uint_as_float(r2.y);
            float w3 = __uint_as_float(r3.y);
            float x0, y0, z0, w0v, x1, y1, z1, w1v, x2, y2, z2, w2v, x3, y3, z3, w3v;
            row4(m + (size_t)s0 * 64, cl, x0, y0, z0, w0v);
            row4(m + (size_t)s1 * 64, cl, x1, y1, z1, w1v);
            row4(m + (size_t)s2 * 64, cl, x2, y2, z2, w2v);
            row4(m + (size_t)s3 * 64, cl, x3, y3, z3, w3v);
            ax = fmaf(w0, x0, ax); ay = fmaf(w0, y0, ay);
            az = fmaf(w0, z0, az); aw = fmaf(w0, w0v, aw);
            ax = fmaf(w1, x1, ax); ay = fmaf(w1, y1, ay);
            az = fmaf(w1, z1, az); aw = fmaf(w1, w1v, aw);
            ax = fmaf(w2, x2, ax); ay = fmaf(w2, y2, ay);
            az = fmaf(w2, z2, az); aw = fmaf(w2, w2v, aw);
            ax = fmaf(w3, x3, ax); ay = fmaf(w3, y3, ay);
            az = fmaf(w3, z3, az); aw = fmaf(w3, w3v, aw);
        }
        for (; e < e1; e++) {
            uint2 rr = csr[e];
            int s = (int)rr.x;
            float w = __uint_as_float(rr.y);
            float xs, ys, zs, wsv;
            row4(m + (size_t)s * 64, cl, xs, ys, zs, wsv);
            ax = fmaf(w, xs, ax);
            ay = fmaf(w, ys, ay);
            az = fmaf(w, zs, az);
            aw = fmaf(w, wsv, aw);
        }
        float4 hb = ((const float4*)(h + (size_t)i * 64))[cl];
        float nx = hb.x + fmaxf(ax + cbv.x, 0.f);
        float ny = hb.y + fmaxf(ay + cbv.y, 0.f);
        float nz = hb.z + fmaxf(az + cbv.z, 0.f);
        float nw = hb.w + fmaxf(aw + cbv.w, 0.f);
        if (writeH) {
            float4 o; o.x = nx; o.y = ny; o.z = nz; o.w = nw;
            ((float4*)(h + (size_t)i * 64))[cl] = o;
        }
        if (stats) {
            sx += nx; sy += ny; sz += nz; sw += nw;
            qx = fmaf(nx, nx, qx); qy = fmaf(ny, ny, qy);
            qz = fmaf(nz, nz, qz); qw = fmaf(nw, nw, qw);
        }
        if (pooled) {
            int g = batch[i];
            float* p = pooled + g * 64 + cl * 4;
            atomicAdd(p + 0, nx);
            atomicAdd(p + 1, ny);
            atomicAdd(p + 2, nz);
            atomicAdd(p + 3, nw);
        }
    }
    if (stats) {
        __shared__ float rs[256 * 4];
        __shared__ float rq[256 * 4];
        rs[tid * 4 + 0] = sx; rs[tid * 4 + 1] = sy; rs[tid * 4 + 2] = sz; rs[tid * 4 + 3] = sw;
        rq[tid * 4 + 0] = qx; rq[tid * 4 + 1] = qy; rq[tid * 4 + 2] = qz; rq[tid * 4 + 3] = qw;
        __syncthreads();
        if (tid < 64) {  // tid = cl*4+k  -> column cl*4+k
            int cl2 = tid >> 2, k = tid & 3;
            float a = 0.f, b = 0.f;
            for (int g = 0; g < 16; g++) {
                a += rs[(g * 16 + cl2) * 4 + k];
                b += rq[(g * 16 + cl2) * 4 + k];
            }
            atomicAdd(&stats[tid], a);
            atomicAdd(&stats[64 + tid], b);
        }
    }
}

// ---- final BN apply ----
__global__ void bn_apply(const float* __restrict__ A, const float* __restrict__ stats, float count,
                         const float* __restrict__ g, const float* __restrict__ b,
                         float* __restrict__ out, int total) {
    int idx = blockIdx.x * 256 + threadIdx.x;
    if (idx < total) {
        int j = idx & 63;
        float mu  = stats[j] / count;
        float var = fmaxf(stats[64 + j] / count - mu * mu, 0.f);
        float rstd = rsqrtf(var + 1e-5f);
        out[idx] = (A[idx] - mu) * rstd * g[j] + b[j];
    }
}

extern "C" void kernel_launch(void* const* d_in, const int* in_sizes, int n_in,
                              void* d_out, int out_size, void* d_ws, size_t ws_size,
                              hipStream_t stream) {
    const float* x     = (const float*)d_in[0];
    const int*   ei    = (const int*)d_in[1];
    const int*   batch = (const int*)d_in[2];
    const float* bnfg  = (const float*)d_in[3];
    const float* bnfb  = (const float*)d_in[4];
    const float* linW  = (const float*)d_in[5];
    const float* linb  = (const float*)d_in[6];
    const float* bncg  = (const float*)d_in[7];
    const float* bncb  = (const float*)d_in[8];
    const float* convW = (const float*)d_in[9];
    const float* convb = (const float*)d_in[10];
    const float* bnfcg = (const float*)d_in[11];
    const float* bnfcb = (const float*)d_in[12];
    const float* fcW   = (const float*)d_in[13];
    const float* fcb   = (const float*)d_in[14];
    const float* bnhg  = (const float*)d_in[15];
    const float* bnhb  = (const float*)d_in[16];

    const int N64 = NN * 64;
    float* ws = (float*)d_ws;
    size_t o = 0;
    int*   cnt      = (int*)(ws + o);   o += 100352;
    float* dinv     = ws + o;           o += 100352;
    int*   row_ptr  = (int*)(ws + o);   o += 100352;
    int*   cursor   = (int*)(ws + o);   o += 100352;
    int*   bsum     = (int*)(ws + o);   o += 512;
    uint2* csr      = (uint2*)(ws + o); o += 2 * EE;     // packed 8B records
    float* h        = ws + o;           o += N64;        // fp32 residual state
    __half* m16     = (__half*)(ws + o); o += N64 / 2;   // fp16 rows, 128B each
    float* statsA   = ws + o;           o += 128;
    float* statsB   = ws + o;           o += 128;
    float* pa       = ws + o;           o += GG * 64;
    float* pb       = ws + o;           o += GG * 64;

    // --- CSR build ---
    hipMemsetAsync(cnt, 0, NN * sizeof(int), stream);
    deg_kernel<<<(EE + 255) / 256, 256, 0, stream>>>(ei, cnt, EE);
    dinv_kernel<<<NB, 256, 0, stream>>>(cnt, dinv, NN);
    blocksum<<<NB, 256, 0, stream>>>(cnt, bsum);
    scan_bsum<<<1, 512, 0, stream>>>(bsum, NB);
    scan_final<<<NB, 256, 0, stream>>>(cnt, bsum, row_ptr, cursor);
    fill_csr<<<(EE + 255) / 256, 256, 0, stream>>>(ei, dinv, cursor, csr, EE);

    // --- stem: h = relu(BN(x)@linW + linb) with fused fold + stats(h) -> statsB ---
    hipMemsetAsync(statsA, 0, 512, stream);
    colstats<<<256, 256, 0, stream>>>(x, NN, statsA);
    hipMemsetAsync(statsB, 0, 512, stream);
    gemm64f<<<(NN + 63) / 64, 256, 0, stream>>>(x, linW, bnfg, bnfb, linb,
                                                statsA, (float)NN, h, nullptr, NN, 1, statsB);

    // --- conv layers ---
    hipMemsetAsync(pa, 0, GG * 64 * sizeof(float), stream);
    float* cur = statsB; float* nxt = statsA;
    for (int l = 0; l < 4; l++) {
        gemm64f<<<(NN + 63) / 64, 256, 0, stream>>>(h, convW + 4096 * l,
                                                    bncg + 64 * l, bncb + 64 * l, nullptr,
                                                    cur, (float)NN, nullptr, m16, NN, 0, nullptr);
        if (l < 3) {
            hipMemsetAsync(nxt, 0, 512, stream);
            gather<<<2048, 256, 0, stream>>>(row_ptr, csr, dinv, m16, h,
                                             convb + 64 * l, nxt, nullptr, batch, 1);
        } else {
            gather<<<2048, 256, 0, stream>>>(row_ptr, csr, dinv, m16, h,
                                             convb + 64 * l, nullptr, pa, batch, 0);
        }
        float* t = cur; cur = nxt; nxt = t;
    }

    // --- fc head (fused fold) ---
    float* pin = pa; float* pout = pb;
    for (int i = 0; i < 2; i++) {
        hipMemsetAsync(statsA, 0, 512, stream);
        colstats<<<8, 256, 0, stream>>>(pin, GG, statsA);
        gemm64f<<<(GG + 63) / 64, 256, 0, stream>>>(pin, fcW + 4096 * i,
                                                    bnfcg + 64 * i, bnfcb + 64 * i, fcb + 64 * i,
                                                    statsA, (float)GG, pout, nullptr, GG, 1, nullptr);
        float* t = pin; pin = pout; pout = t;
    }

    // --- final BN -> d_out ---
    hipMemsetAsync(statsA, 0, 512, stream);
    colstats<<<8, 256, 0, stream>>>(pin, GG, statsA);
    bn_apply<<<(GG * 64 + 255) / 256, 256, 0, stream>>>(pin, statsA, (float)GG, bnhg, bnhb,
                                                        (float*)d_out, GG * 64);
}

// Round 10
// 1048.172 us; speedup vs baseline: 1.0287x; 1.0287x over previous
//
#include <hip/hip_runtime.h>
#include <hip/hip_fp16.h>

#define NN 100000
#define EE 1600000
#define GG 512
#define NB ((NN + 255) / 256)   // 391 blocks for node-sized scans

// ---- in-degree histogram (int) ----
__global__ void deg_kernel(const int* __restrict__ ei, int* __restrict__ cnt, int E_) {
    int e = blockIdx.x * 256 + threadIdx.x;
    if (e < E_) atomicAdd(&cnt[ei[E_ + e]], 1);
}

// ---- dinv = 1/sqrt(cnt + 1 self-loop) ----
__global__ void dinv_kernel(const int* __restrict__ cnt, float* __restrict__ dinv, int n) {
    int i = blockIdx.x * 256 + threadIdx.x;
    if (i < n) dinv[i] = rsqrtf((float)cnt[i] + 1.0f);
}

// ---- block sums for scan ----
__global__ void blocksum(const int* __restrict__ cnt, int* __restrict__ bsum) {
    __shared__ int sh[256];
    int i = blockIdx.x * 256 + threadIdx.x;
    sh[threadIdx.x] = (i < NN) ? cnt[i] : 0;
    __syncthreads();
    for (int o = 128; o > 0; o >>= 1) {
        if (threadIdx.x < o) sh[threadIdx.x] += sh[threadIdx.x + o];
        __syncthreads();
    }
    if (threadIdx.x == 0) bsum[blockIdx.x] = sh[0];
}

// ---- exclusive scan of block sums (1 block, 512 threads, nb<=512) ----
__global__ void scan_bsum(int* __restrict__ bsum, int nb) {
    __shared__ int sh[512];
    int t = threadIdx.x;
    int v = (t < nb) ? bsum[t] : 0;
    int orig = v;
    sh[t] = v;
    __syncthreads();
    for (int o = 1; o < 512; o <<= 1) {
        int add = (t >= o) ? sh[t - o] : 0;
        __syncthreads();
        sh[t] += add;
        __syncthreads();
    }
    if (t < nb) bsum[t] = sh[t] - orig;   // exclusive
}

// ---- final scan: row_ptr + cursor ----
__global__ void scan_final(const int* __restrict__ cnt, const int* __restrict__ boff,
                           int* __restrict__ row_ptr, int* __restrict__ cursor) {
    __shared__ int sh[256];
    int i = blockIdx.x * 256 + threadIdx.x;
    int v = (i < NN) ? cnt[i] : 0;
    int orig = v;
    sh[threadIdx.x] = v;
    __syncthreads();
    for (int o = 1; o < 256; o <<= 1) {
        int add = (threadIdx.x >= o) ? sh[threadIdx.x - o] : 0;
        __syncthreads();
        sh[threadIdx.x] += add;
        __syncthreads();
    }
    if (i < NN) {
        int ex = boff[blockIdx.x] + sh[threadIdx.x] - orig;
        row_ptr[i] = ex;
        cursor[i] = ex;
    }
    if (i == 0) row_ptr[NN] = EE;
}

// ---- fill CSR: one packed 8B record per edge {src, norm=dinv[s]*dinv[d]} ----
__global__ void fill_csr(const int* __restrict__ ei, const float* __restrict__ dinv,
                         int* __restrict__ cursor, uint2* __restrict__ csr, int E_) {
    int e = blockIdx.x * 256 + threadIdx.x;
    if (e < E_) {
        int s = ei[e], d = ei[E_ + e];
        int pos = atomicAdd(&cursor[d], 1);
        uint2 rec;
        rec.x = (unsigned)s;
        rec.y = __float_as_uint(dinv[s] * dinv[d]);
        csr[pos] = rec;
    }
}

// ---- column stats: stats[0:64]=sum, stats[64:128]=sumsq (fp32 input) ----
__global__ void colstats(const float* __restrict__ A, int nrows, float* __restrict__ stats) {
    __shared__ float ssum[4][64];
    __shared__ float ssq[4][64];
    int tid = threadIdx.x;
    int col = tid & 63, rg = tid >> 6;
    float s = 0.f, q = 0.f;
    for (int r = blockIdx.x * 4 + rg; r < nrows; r += gridDim.x * 4) {
        float v = A[r * 64 + col];
        s += v;
        q = fmaf(v, v, q);
    }
    ssum[rg][col] = s; ssq[rg][col] = q;
    __syncthreads();
    if (tid < 64) {
        float ts = ssum[0][tid] + ssum[1][tid] + ssum[2][tid] + ssum[3][tid];
        float tq = ssq[0][tid] + ssq[1][tid] + ssq[2][tid] + ssq[3][tid];
        atomicAdd(&stats[tid], ts);
        atomicAdd(&stats[64 + tid], tq);
    }
}

// ---- fused BN-fold + C = (relu?)(BN(A)@W + basebias); A fp32 OR fp16;
//      C fp32 and/or fp16; optional fused column stats of C ----
__global__ __launch_bounds__(256) void gemm64f(const float* __restrict__ A32,
                                               const __half* __restrict__ A16,
                                               const float* __restrict__ W,
                                               const float* __restrict__ g,
                                               const float* __restrict__ b,
                                               const float* __restrict__ basebias,
                                               const float* __restrict__ statsIn, float count,
                                               float* __restrict__ C32,
                                               __half* __restrict__ C16,
                                               int nrows, int dorelu,
                                               float* __restrict__ statsOut) {
    __shared__ float Ws[64 * 64];
    __shared__ float As[64 * 64];
    __shared__ float afold[64];
    __shared__ float cfold[64];
    __shared__ float ssh[256];
    __shared__ float qsh[256];
    int tid = threadIdx.x;
    if (tid < 64) {
        float mu  = statsIn[tid] / count;
        float var = fmaxf(statsIn[64 + tid] / count - mu * mu, 0.f);
        float rstd = rsqrtf(var + 1e-5f);
        float a = rstd * g[tid];
        afold[tid] = a;
        cfold[tid] = b[tid] - mu * a;
    }
    __syncthreads();
    int row0 = blockIdx.x * 64;
    // stage folded W and A
    if (A32) {
        for (int i = tid; i < 4096; i += 256) {
            Ws[i] = afold[i >> 6] * W[i];
            int r = row0 + (i >> 6);
            As[i] = (r < nrows) ? A32[row0 * 64 + i] : 0.f;
        }
    } else {
        for (int i = tid; i < 4096; i += 256) Ws[i] = afold[i >> 6] * W[i];
        const uint4* Av = (const uint4*)(A16 + (size_t)row0 * 64);
#pragma unroll
        for (int p = 0; p < 2; p++) {
            int idx = tid + 256 * p;          // 0..511, 8 halves per uint4
            int r = row0 + (idx >> 3);
            if (r < nrows) {
                uint4 raw = Av[idx];
                const __half2* hp = (const __half2*)&raw;
#pragma unroll
                for (int t = 0; t < 4; t++) {
                    float2 v = __half22float2(hp[t]);
                    As[idx * 8 + 2 * t]     = v.x;
                    As[idx * 8 + 2 * t + 1] = v.y;
                }
            } else {
#pragma unroll
                for (int t = 0; t < 8; t++) As[idx * 8 + t] = 0.f;
            }
        }
    }
    __syncthreads();
    int col = tid & 63;
    int rg = tid >> 6;  // 0..3
    // folded bias for this column
    float bcol = basebias ? basebias[col] : 0.f;
    for (int k = 0; k < 64; k++) bcol = fmaf(cfold[k], W[k * 64 + col], bcol);
    float s = 0.f, q = 0.f;
    for (int rr = rg; rr < 64; rr += 4) {
        int r = row0 + rr;
        if (r >= nrows) break;
        float acc = bcol;
#pragma unroll
        for (int k = 0; k < 64; k++) acc = fmaf(As[rr * 64 + k], Ws[k * 64 + col], acc);
        float v = dorelu ? fmaxf(acc, 0.f) : acc;
        if (C32) C32[r * 64 + col] = v;
        if (C16) C16[r * 64 + col] = __float2half(v);
        s += v;
        q = fmaf(v, v, q);
    }
    if (statsOut) {
        ssh[tid] = s; qsh[tid] = q;
        __syncthreads();
        if (tid < 64) {
            float ts = ssh[tid] + ssh[64 + tid] + ssh[128 + tid] + ssh[192 + tid];
            float tq = qsh[tid] + qsh[64 + tid] + qsh[128 + tid] + qsh[192 + tid];
            atomicAdd(&statsOut[tid], ts);
            atomicAdd(&statsOut[64 + tid], tq);
        }
    }
}

// ---- unpack 4 consecutive fp16 feats (8B) from a row ----
__device__ __forceinline__ void row4(const __half* __restrict__ base, int cl,
                                     float& x, float& y, float& z, float& w) {
    uint2 raw = ((const uint2*)base)[cl];
    __half2 h01 = *reinterpret_cast<const __half2*>(&raw.x);
    __half2 h23 = *reinterpret_cast<const __half2*>(&raw.y);
    float2 f01 = __half22float2(h01);
    float2 f23 = __half22float2(h23);
    x = f01.x; y = f01.y; z = f23.x; w = f23.y;
}
__device__ __forceinline__ void h4store(__half* __restrict__ base, int cl,
                                        float x, float y, float z, float w) {
    __half2 a = __float22half2_rn(make_float2(x, y));
    __half2 b = __float22half2_rn(make_float2(z, w));
    uint2 raw;
    raw.x = *reinterpret_cast<unsigned*>(&a);
    raw.y = *reinterpret_cast<unsigned*>(&b);
    ((uint2*)base)[cl] = raw;
}

// ---- fused CSR gather (m,h fp16; packed 8B edge records):
//      hn = h + relu(dinv^2*m[i] + sum_e norm*m[src] + cb)
//      one streaming 8B load per edge + one random m-row probe (the minimum).
//      optional: write h, next-layer BN stats, atomic pool ----
__global__ __launch_bounds__(256) void gather(const int* __restrict__ row_ptr,
                                              const uint2* __restrict__ csr,
                                              const float* __restrict__ dinv,
                                              const __half* __restrict__ m,
                                              __half* __restrict__ h,
                                              const float* __restrict__ cb,
                                              float* __restrict__ stats,
                                              float* __restrict__ pooled,
                                              const int* __restrict__ batch,
                                              int writeH) {
    int tid = threadIdx.x;
    int ng = tid >> 4;        // 16 nodes per block
    int cl = tid & 15;        // 16 col-groups of 4
    const float4* cb4 = (const float4*)cb;
    float4 cbv = cb4[cl];
    float sx = 0.f, sy = 0.f, sz = 0.f, sw = 0.f;
    float qx = 0.f, qy = 0.f, qz = 0.f, qw = 0.f;
    for (int i = blockIdx.x * 16 + ng; i < NN; i += gridDim.x * 16) {
        float di = dinv[i];
        float mx, my, mz, mw;
        row4(m + (size_t)i * 64, cl, mx, my, mz, mw);
        float d2 = di * di;
        float ax = d2 * mx, ay = d2 * my, az = d2 * mz, aw = d2 * mw;
        int e0 = row_ptr[i], e1 = row_ptr[i + 1];
        int e = e0;
        // 4-wide unroll: 4 independent row loads in flight per node-group
        for (; e + 3 < e1; e += 4) {
            uint2 r0 = csr[e + 0];
            uint2 r1 = csr[e + 1];
            uint2 r2 = csr[e + 2];
            uint2 r3 = csr[e + 3];
            int s0 = (int)r0.x, s1 = (int)r1.x, s2 = (int)r2.x, s3 = (int)r3.x;
            float w0 = __uint_as_float(r0.y);
            float w1 = __uint_as_float(r1.y);
            float w2 = __uint_as_float(r2.y);
            float w3 = __uint_as_float(r3.y);
            float x0, y0, z0, w0v, x1, y1, z1, w1v, x2, y2, z2, w2v, x3, y3, z3, w3v;
            row4(m + (size_t)s0 * 64, cl, x0, y0, z0, w0v);
            row4(m + (size_t)s1 * 64, cl, x1, y1, z1, w1v);
            row4(m + (size_t)s2 * 64, cl, x2, y2, z2, w2v);
            row4(m + (size_t)s3 * 64, cl, x3, y3, z3, w3v);
            ax = fmaf(w0, x0, ax); ay = fmaf(w0, y0, ay);
            az = fmaf(w0, z0, az); aw = fmaf(w0, w0v, aw);
            ax = fmaf(w1, x1, ax); ay = fmaf(w1, y1, ay);
            az = fmaf(w1, z1, az); aw = fmaf(w1, w1v, aw);
            ax = fmaf(w2, x2, ax); ay = fmaf(w2, y2, ay);
            az = fmaf(w2, z2, az); aw = fmaf(w2, w2v, aw);
            ax = fmaf(w3, x3, ax); ay = fmaf(w3, y3, ay);
            az = fmaf(w3, z3, az); aw = fmaf(w3, w3v, aw);
        }
        for (; e < e1; e++) {
            uint2 rr = csr[e];
            int s = (int)rr.x;
            float w = __uint_as_float(rr.y);
            float xs, ys, zs, wsv;
            row4(m + (size_t)s * 64, cl, xs, ys, zs, wsv);
            ax = fmaf(w, xs, ax);
            ay = fmaf(w, ys, ay);
            az = fmaf(w, zs, az);
            aw = fmaf(w, wsv, aw);
        }
        float hx, hy, hz, hw;
        row4(h + (size_t)i * 64, cl, hx, hy, hz, hw);
        float nx = hx + fmaxf(ax + cbv.x, 0.f);
        float ny = hy + fmaxf(ay + cbv.y, 0.f);
        float nz = hz + fmaxf(az + cbv.z, 0.f);
        float nw = hw + fmaxf(aw + cbv.w, 0.f);
        if (writeH) {
            h4store(h + (size_t)i * 64, cl, nx, ny, nz, nw);
        }
        if (stats) {
            sx += nx; sy += ny; sz += nz; sw += nw;
            qx = fmaf(nx, nx, qx); qy = fmaf(ny, ny, qy);
            qz = fmaf(nz, nz, qz); qw = fmaf(nw, nw, qw);
        }
        if (pooled) {
            int g = batch[i];
            float* p = pooled + g * 64 + cl * 4;
            atomicAdd(p + 0, nx);
            atomicAdd(p + 1, ny);
            atomicAdd(p + 2, nz);
            atomicAdd(p + 3, nw);
        }
    }
    if (stats) {
        __shared__ float rs[256 * 4];
        __shared__ float rq[256 * 4];
        rs[tid * 4 + 0] = sx; rs[tid * 4 + 1] = sy; rs[tid * 4 + 2] = sz; rs[tid * 4 + 3] = sw;
        rq[tid * 4 + 0] = qx; rq[tid * 4 + 1] = qy; rq[tid * 4 + 2] = qz; rq[tid * 4 + 3] = qw;
        __syncthreads();
        if (tid < 64) {  // tid = cl*4+k  -> column cl*4+k
            int cl2 = tid >> 2, k = tid & 3;
            float a = 0.f, b = 0.f;
            for (int g = 0; g < 16; g++) {
                a += rs[(g * 16 + cl2) * 4 + k];
                b += rq[(g * 16 + cl2) * 4 + k];
            }
            atomicAdd(&stats[tid], a);
            atomicAdd(&stats[64 + tid], b);
        }
    }
}

// ---- final BN apply ----
__global__ void bn_apply(const float* __restrict__ A, const float* __restrict__ stats, float count,
                         const float* __restrict__ g, const float* __restrict__ b,
                         float* __restrict__ out, int total) {
    int idx = blockIdx.x * 256 + threadIdx.x;
    if (idx < total) {
        int j = idx & 63;
        float mu  = stats[j] / count;
        float var = fmaxf(stats[64 + j] / count - mu * mu, 0.f);
        float rstd = rsqrtf(var + 1e-5f);
        out[idx] = (A[idx] - mu) * rstd * g[j] + b[j];
    }
}

extern "C" void kernel_launch(void* const* d_in, const int* in_sizes, int n_in,
                              void* d_out, int out_size, void* d_ws, size_t ws_size,
                              hipStream_t stream) {
    const float* x     = (const float*)d_in[0];
    const int*   ei    = (const int*)d_in[1];
    const int*   batch = (const int*)d_in[2];
    const float* bnfg  = (const float*)d_in[3];
    const float* bnfb  = (const float*)d_in[4];
    const float* linW  = (const float*)d_in[5];
    const float* linb  = (const float*)d_in[6];
    const float* bncg  = (const float*)d_in[7];
    const float* bncb  = (const float*)d_in[8];
    const float* convW = (const float*)d_in[9];
    const float* convb = (const float*)d_in[10];
    const float* bnfcg = (const float*)d_in[11];
    const float* bnfcb = (const float*)d_in[12];
    const float* fcW   = (const float*)d_in[13];
    const float* fcb   = (const float*)d_in[14];
    const float* bnhg  = (const float*)d_in[15];
    const float* bnhb  = (const float*)d_in[16];

    const int N64 = NN * 64;
    float* ws = (float*)d_ws;
    size_t o = 0;
    int*   cnt      = (int*)(ws + o);   o += 100352;
    float* dinv     = ws + o;           o += 100352;
    int*   row_ptr  = (int*)(ws + o);   o += 100352;
    int*   cursor   = (int*)(ws + o);   o += 100352;
    int*   bsum     = (int*)(ws + o);   o += 512;
    uint2* csr      = (uint2*)(ws + o); o += 2 * EE;     // packed 8B records
    __half* h16     = (__half*)(ws + o); o += N64 / 2;   // fp16 rows, 128B each
    __half* m16     = (__half*)(ws + o); o += N64 / 2;   // fp16 rows, 128B each
    float* spool    = ws + o;           o += 8 * 128;    // 8 stats buffers, one memset
    float* pa       = ws + o;           o += GG * 64;
    float* pb       = ws + o;           o += GG * 64;

    float* S0 = spool + 0 * 128;   // stats(x)
    float* S1 = spool + 1 * 128;   // stats(h) after stem
    float* S2 = spool + 2 * 128;   // stats(h) after conv0
    float* S3 = spool + 3 * 128;   // stats(h) after conv1
    float* S4 = spool + 4 * 128;   // stats(h) after conv2
    float* S5 = spool + 5 * 128;   // stats(pooled) fc0
    float* S6 = spool + 6 * 128;   // stats fc1
    float* S7 = spool + 7 * 128;   // stats final BN

    // --- one-shot zeroing of all stats buffers + pool ---
    hipMemsetAsync(spool, 0, 8 * 128 * sizeof(float), stream);
    hipMemsetAsync(pa, 0, GG * 64 * sizeof(float), stream);
    hipMemsetAsync(cnt, 0, NN * sizeof(int), stream);

    // --- CSR build ---
    deg_kernel<<<(EE + 255) / 256, 256, 0, stream>>>(ei, cnt, EE);
    dinv_kernel<<<NB, 256, 0, stream>>>(cnt, dinv, NN);
    blocksum<<<NB, 256, 0, stream>>>(cnt, bsum);
    scan_bsum<<<1, 512, 0, stream>>>(bsum, NB);
    scan_final<<<NB, 256, 0, stream>>>(cnt, bsum, row_ptr, cursor);
    fill_csr<<<(EE + 255) / 256, 256, 0, stream>>>(ei, dinv, cursor, csr, EE);

    // --- stem: h16 = relu(BN(x)@linW + linb) fused fold + stats(h) -> S1 ---
    colstats<<<256, 256, 0, stream>>>(x, NN, S0);
    gemm64f<<<(NN + 63) / 64, 256, 0, stream>>>(x, nullptr, linW, bnfg, bnfb, linb,
                                                S0, (float)NN, nullptr, h16, NN, 1, S1);

    // --- conv layers ---
    float* convStats[5] = {S1, S2, S3, S4, nullptr};
    for (int l = 0; l < 4; l++) {
        gemm64f<<<(NN + 63) / 64, 256, 0, stream>>>(nullptr, h16, convW + 4096 * l,
                                                    bncg + 64 * l, bncb + 64 * l, nullptr,
                                                    convStats[l], (float)NN, nullptr, m16, NN, 0, nullptr);
        if (l < 3) {
            gather<<<2048, 256, 0, stream>>>(row_ptr, csr, dinv, m16, h16,
                                             convb + 64 * l, convStats[l + 1], nullptr, batch, 1);
        } else {
            gather<<<2048, 256, 0, stream>>>(row_ptr, csr, dinv, m16, h16,
                                             convb + 64 * l, nullptr, pa, batch, 0);
        }
    }

    // --- fc head (fused fold) ---
    colstats<<<8, 256, 0, stream>>>(pa, GG, S5);
    gemm64f<<<(GG + 63) / 64, 256, 0, stream>>>(pa, nullptr, fcW,
                                                bnfcg, bnfcb, fcb,
                                                S5, (float)GG, pb, nullptr, GG, 1, nullptr);
    colstats<<<8, 256, 0, stream>>>(pb, GG, S6);
    gemm64f<<<(GG + 63) / 64, 256, 0, stream>>>(pb, nullptr, fcW + 4096,
                                                bnfcg + 64, bnfcb + 64, fcb + 64,
                                                S6, (float)GG, pa, nullptr, GG, 1, nullptr);

    // --- final BN -> d_out ---
    colstats<<<8, 256, 0, stream>>>(pa, GG, S7);
    bn_apply<<<(GG * 64 + 255) / 256, 256, 0, stream>>>(pa, S7, (float)GG, bnhg, bnhb,
                                                        (float*)d_out, GG * 64);
}